// Round 1
// baseline (12954.524 us; speedup 1.0000x reference)
//
#include <hip/hip_runtime.h>
#include <math.h>

#define NL 18
#define WIDTH 1024
#define NH 8
#define HD 256
#define MLP_DIM 4096
#define AH 50
#define AD 32
#define BZ 4
#define PFX 968
#define TT (PFX + AH)      // 1018
#define ROWS (BZ * AH)     // 200

// ---------------- time embedding ----------------
__global__ __launch_bounds__(1024) void k_time_embed(const float* __restrict__ t,
                                                     float* __restrict__ emb) {
  int b = blockIdx.x;
  int d = threadIdx.x;                 // 0..1023
  int i = d & 511;
  double frac = (double)i / 511.0;
  double period = 0.004 * exp(frac * log(1000.0));
  double w = (2.0 * M_PI) / period;
  double si = w * (double)t[b];
  emb[b * 1024 + d] = (d < 512) ? (float)sin(si) : (float)cos(si);
}

// ---------------- small GEMV (4x1024 @ 1024x1024), split-K two-stage ----------------
__global__ __launch_bounds__(256) void k_gemv_part(const float* __restrict__ A,
                                                   const float* __restrict__ W,
                                                   float* __restrict__ part) {
  int j = blockIdx.x * 256 + threadIdx.x;   // 0..1023
  int kc = blockIdx.y;                      // 0..15
  int b = blockIdx.z;                       // 0..3
  const float* a = A + b * 1024 + kc * 64;
  const float* w = W + (size_t)(kc * 64) * 1024 + j;
  float acc = 0.f;
#pragma unroll
  for (int k = 0; k < 64; ++k) acc = fmaf(a[k], w[(size_t)k * 1024], acc);
  part[((size_t)b * 16 + kc) * 1024 + j] = acc;
}

// mode 0: silu(x + bias) ; mode 1: 1 + bias + x   (bias = wvec)
__global__ __launch_bounds__(256) void k_gemv_fin(const float* __restrict__ part,
                                                  const float* __restrict__ bias,
                                                  float* __restrict__ out, int mode) {
  int idx = blockIdx.x * 256 + threadIdx.x;  // 0..4095
  int b = idx >> 10, j = idx & 1023;
  float acc = 0.f;
#pragma unroll
  for (int c = 0; c < 16; ++c) acc += part[((size_t)b * 16 + c) * 1024 + j];
  if (mode == 0) { acc += bias[j]; out[idx] = acc / (1.f + expf(-acc)); }
  else out[idx] = 1.f + bias[j] + acc;
}

// ---------------- input embedding: h = (x_t @ w_act_in + b) * 32 ----------------
__global__ __launch_bounds__(256) void k_embed(const float* __restrict__ x,
                                               const float* __restrict__ W,
                                               const float* __restrict__ bias,
                                               float* __restrict__ h) {
  int idx = blockIdx.x * 256 + threadIdx.x;  // 204800
  int row = idx >> 10, dd = idx & 1023;
  const float* xr = x + row * AD;
  float acc = bias[dd];
#pragma unroll
  for (int k = 0; k < AD; ++k) acc = fmaf(xr[k], W[(size_t)k * WIDTH + dd], acc);
  h[idx] = acc * 32.f;   // sqrt(1024)
}

// ---------------- adaptive RMSNorm apply ----------------
__global__ __launch_bounds__(256) void k_rmsnorm(const float* __restrict__ x,
                                                 const float* __restrict__ scl,
                                                 float* __restrict__ out) {
  int row = blockIdx.x;
  int b = row / AH;
  __shared__ float red[256];
  const float* xr = x + (size_t)row * WIDTH;
  float s = 0.f;
  for (int d = threadIdx.x; d < WIDTH; d += 256) { float v = xr[d]; s = fmaf(v, v, s); }
  red[threadIdx.x] = s;
  __syncthreads();
  for (int off = 128; off > 0; off >>= 1) {
    if (threadIdx.x < off) red[threadIdx.x] += red[threadIdx.x + off];
    __syncthreads();
  }
  float r = rsqrtf(red[0] * (1.f / 1024.f) + 1e-6f);
  for (int d = threadIdx.x; d < WIDTH; d += 256)
    out[(size_t)row * WIDTH + d] = xr[d] * r * scl[(size_t)b * WIDTH + d];
}

// ---------------- big GEMM: C[M=200,N] (+)= A[200,K] @ W[K,N], split-K atomics ----
// block: 256 threads, 16 rows x 512 cols; grid (N/512 ceil, 13, K/256)
__global__ __launch_bounds__(256) void k_gemm(const float* __restrict__ A,
                                              const float* __restrict__ W,
                                              float* __restrict__ C, int K, int N) {
  const int row0 = blockIdx.y * 16;
  const int col0 = blockIdx.x * 512 + threadIdx.x;
  const int col1 = col0 + 256;
  const bool c1ok = (col1 < N);
  const int k0 = blockIdx.z * 256;
  float acc0[16], acc1[16];
#pragma unroll
  for (int m = 0; m < 16; ++m) { acc0[m] = 0.f; acc1[m] = 0.f; }
  const float* w0p = W + (size_t)k0 * N;
  for (int k = 0; k < 256; k += 4) {
    float4 av[16];
#pragma unroll
    for (int m = 0; m < 16; ++m) {
      int rr = row0 + m; if (rr > ROWS - 1) rr = ROWS - 1;
      av[m] = *(const float4*)(A + (size_t)rr * K + k0 + k);
    }
#pragma unroll
    for (int kk = 0; kk < 4; ++kk) {
      const float w0 = w0p[(size_t)(k + kk) * N + col0];
      const float w1 = c1ok ? w0p[(size_t)(k + kk) * N + col1] : 0.f;
#pragma unroll
      for (int m = 0; m < 16; ++m) {
        const float a = (&av[m].x)[kk];
        acc0[m] = fmaf(a, w0, acc0[m]);
        acc1[m] = fmaf(a, w1, acc1[m]);
      }
    }
  }
#pragma unroll
  for (int m = 0; m < 16; ++m) {
    if (row0 + m < ROWS) {
      float* cr = C + (size_t)(row0 + m) * N;
      atomicAdd(cr + col0, acc0[m]);
      if (c1ok) atomicAdd(cr + col1, acc1[m]);
    }
  }
}

// ---------------- RoPE in place ----------------
__global__ __launch_bounds__(256) void k_rope(float* __restrict__ x, int nheads) {
  int idx = blockIdx.x * 256 + threadIdx.x;
  int i = idx & 127;
  int t = idx >> 7;
  int hh = t % nheads;
  int row = t / nheads;
  int s = row % AH;
  double inv = exp(-(double)i * (9.210340371976184 / 128.0));  // 10000^(-i/128)
  double fr = (double)(PFX + s) * inv;
  float c = (float)cos(fr), sn = (float)sin(fr);
  float* base = x + ((size_t)row * nheads + hh) * HD;
  float x1 = base[i], x2 = base[i + 128];
  base[i] = x1 * c - x2 * sn;
  base[i + 128] = x2 * c + x1 * sn;
}

// ---------------- attention: one block per (b,s), all 8 heads ----------------
__global__ __launch_bounds__(256) void k_attn(const float* __restrict__ q,
                                              const float* __restrict__ ksuf,
                                              const float* __restrict__ vsuf,
                                              const float* __restrict__ pk,
                                              const float* __restrict__ pv,
                                              float* __restrict__ o, int layer) {
  const int row = blockIdx.x;
  const int b = row / AH;
  const int tid = threadIdx.x;
  __shared__ float qs[NH][HD];          // 8 KB
  __shared__ float sc[NH][1020];        // 32.6 KB (padded for float4)
  __shared__ float red[256];
  __shared__ float denom[NH];

  for (int i = tid; i < NH * HD; i += 256)
    (&qs[0][0])[i] = q[(size_t)row * NH * HD + i] * 0.0625f;  // HD^-0.5
  __syncthreads();

  const float* pkl = pk + ((size_t)layer * BZ + b) * PFX * HD;
  const float* ks = ksuf + (size_t)b * AH * HD;

  // scores
  for (int t = tid; t < TT; t += 256) {
    const float4* kr = (const float4*)((t < PFX) ? (pkl + (size_t)t * HD)
                                                 : (ks + (size_t)(t - PFX) * HD));
    float acc[NH];
#pragma unroll
    for (int hh = 0; hh < NH; ++hh) acc[hh] = 0.f;
    for (int d4 = 0; d4 < HD / 4; ++d4) {
      const float4 kv = kr[d4];
#pragma unroll
      for (int hh = 0; hh < NH; ++hh) {
        const float4 qv = *(const float4*)&qs[hh][d4 * 4];
        acc[hh] = fmaf(qv.x, kv.x, fmaf(qv.y, kv.y, fmaf(qv.z, kv.z, fmaf(qv.w, kv.w, acc[hh]))));
      }
    }
#pragma unroll
    for (int hh = 0; hh < NH; ++hh) sc[hh][t] = acc[hh];
  }
  __syncthreads();

  // softmax per head
  for (int h = 0; h < NH; ++h) {
    float m = -3.0e38f;
    for (int t = tid; t < TT; t += 256) m = fmaxf(m, sc[h][t]);
    red[tid] = m;
    __syncthreads();
    for (int off = 128; off > 0; off >>= 1) {
      if (tid < off) red[tid] = fmaxf(red[tid], red[tid + off]);
      __syncthreads();
    }
    m = red[0];
    __syncthreads();
    float ssum = 0.f;
    for (int t = tid; t < TT; t += 256) {
      float p = expf(sc[h][t] - m);
      sc[h][t] = p;
      ssum += p;
    }
    red[tid] = ssum;
    __syncthreads();
    for (int off = 128; off > 0; off >>= 1) {
      if (tid < off) red[tid] += red[tid + off];
      __syncthreads();
    }
    if (tid == 0) denom[h] = red[0];
    __syncthreads();
  }

  // o = p @ V   (thread = dim d, all heads)
  const float* pvl = pv + ((size_t)layer * BZ + b) * PFX * HD;
  const float* vs = vsuf + (size_t)b * AH * HD;
  const int d = tid;
  float oacc[NH];
#pragma unroll
  for (int hh = 0; hh < NH; ++hh) oacc[hh] = 0.f;
  int t = 0;
  for (; t + 4 <= TT; t += 4) {   // PFX=968 is 4-aligned: chunks never straddle
    const float* vbase = (t < PFX) ? (pvl + (size_t)t * HD) : (vs + (size_t)(t - PFX) * HD);
    float v0 = vbase[d], v1 = vbase[HD + d], v2 = vbase[2 * HD + d], v3 = vbase[3 * HD + d];
#pragma unroll
    for (int hh = 0; hh < NH; ++hh) {
      const float4 p4 = *(const float4*)&sc[hh][t];
      oacc[hh] = fmaf(p4.x, v0, fmaf(p4.y, v1, fmaf(p4.z, v2, fmaf(p4.w, v3, oacc[hh]))));
    }
  }
  for (; t < TT; ++t) {
    const float* vbase = (t < PFX) ? (pvl + (size_t)t * HD) : (vs + (size_t)(t - PFX) * HD);
    float v0 = vbase[d];
#pragma unroll
    for (int hh = 0; hh < NH; ++hh) oacc[hh] = fmaf(sc[hh][t], v0, oacc[hh]);
  }
#pragma unroll
  for (int hh = 0; hh < NH; ++hh)
    o[(size_t)row * NH * HD + hh * HD + d] = oacc[hh] / denom[hh];
}

// ---------------- gelu(gate) * up, in place into g ----------------
__global__ __launch_bounds__(256) void k_gelumul(float* __restrict__ g,
                                                 const float* __restrict__ u) {
  int idx = blockIdx.x * 256 + threadIdx.x;
  float x = g[idx];
  float th = tanhf(0.7978845608028654f * (x + 0.044715f * x * x * x));
  g[idx] = 0.5f * x * (1.f + th) * u[idx];
}

// ---------------- final projection (1024 -> 32) ----------------
__global__ __launch_bounds__(256) void k_out(const float* __restrict__ n,
                                             const float* __restrict__ W,
                                             const float* __restrict__ bias,
                                             float* __restrict__ out) {
  int row = blockIdx.x;
  int j = threadIdx.x & 31, kg = threadIdx.x >> 5;   // 8 k-groups x 32 cols
  __shared__ float red[8][32];
  const float* a = n + (size_t)row * WIDTH;
  float acc = 0.f;
  for (int k = kg * 128; k < kg * 128 + 128; ++k)
    acc = fmaf(a[k], W[(size_t)k * AD + j], acc);
  red[kg][j] = acc;
  __syncthreads();
  if (kg == 0) {
    float s = bias[j];
#pragma unroll
    for (int g = 0; g < 8; ++g) s += red[g][j];
    out[(size_t)row * AD + j] = s;
  }
}

extern "C" void kernel_launch(void* const* d_in, const int* in_sizes, int n_in,
                              void* d_out, int out_size, void* d_ws, size_t ws_size,
                              hipStream_t stream) {
  const float* past_keys   = (const float*)d_in[1];
  const float* past_values = (const float*)d_in[2];
  const float* x_t         = (const float*)d_in[3];
  const float* timestep    = (const float*)d_in[4];
  const float* w_act_in    = (const float*)d_in[5];
  const float* b_act_in    = (const float*)d_in[6];
  const float* w_tin       = (const float*)d_in[7];
  const float* b_tin       = (const float*)d_in[8];
  const float* w_tout      = (const float*)d_in[9];
  const float* b_tout      = (const float*)d_in[10];
  const float* w_act_out   = (const float*)d_in[11];
  const float* b_act_out   = (const float*)d_in[12];
  const float* wq          = (const float*)d_in[13];
  const float* wk          = (const float*)d_in[14];
  const float* wv          = (const float*)d_in[15];
  const float* wo          = (const float*)d_in[16];
  const float* w_gate      = (const float*)d_in[17];
  const float* w_up        = (const float*)d_in[18];
  const float* w_down      = (const float*)d_in[19];
  const float* ln1_w       = (const float*)d_in[20];
  const float* ln1_ada     = (const float*)d_in[21];
  const float* ln2_w       = (const float*)d_in[22];
  const float* ln2_ada     = (const float*)d_in[23];
  const float* fin_w       = (const float*)d_in[24];
  const float* fin_ada     = (const float*)d_in[25];

  float* ws = (float*)d_ws;
  float* time_emb = ws;                   // 4096
  float* tmp      = ws + 4096;            // 4096
  float* cond     = ws + 8192;            // 4096
  float* scl      = ws + 12288;           // 4096
  float* h        = ws + 16384;           // 204800
  float* nb       = ws + 221184;          // 204800
  float* qb       = ws + 425984;          // 409600
  float* ksuf     = ws + 835584;          // 51200
  float* vsuf     = ws + 886784;          // 51200
  float* ob       = ws + 937984;          // 409600
  float* mlp_g    = ws + 1347584;         // 819200
  float* mlp_u    = ws + 2166784;         // 819200
  float* part     = ws + 2985984;         // 65536
  float* out      = (float*)d_out;

  // timestep MLP -> cond
  k_time_embed<<<BZ, 1024, 0, stream>>>(timestep, time_emb);
  k_gemv_part<<<dim3(4, 16, BZ), 256, 0, stream>>>(time_emb, w_tin, part);
  k_gemv_fin<<<16, 256, 0, stream>>>(part, b_tin, tmp, 0);
  k_gemv_part<<<dim3(4, 16, BZ), 256, 0, stream>>>(tmp, w_tout, part);
  k_gemv_fin<<<16, 256, 0, stream>>>(part, b_tout, cond, 0);
  // h init
  k_embed<<<800, 256, 0, stream>>>(x_t, w_act_in, b_act_in, h);

  for (int l = 0; l < NL; ++l) {
    const float* wq_l = wq + (size_t)l * WIDTH * (NH * HD);
    const float* wk_l = wk + (size_t)l * WIDTH * HD;
    const float* wv_l = wv + (size_t)l * WIDTH * HD;
    const float* wo_l = wo + (size_t)l * (NH * HD) * WIDTH;
    const float* wg_l = w_gate + (size_t)l * WIDTH * MLP_DIM;
    const float* wu_l = w_up + (size_t)l * WIDTH * MLP_DIM;
    const float* wd_l = w_down + (size_t)l * MLP_DIM * WIDTH;

    // adaRMS 1
    k_gemv_part<<<dim3(4, 16, BZ), 256, 0, stream>>>(cond, ln1_ada + (size_t)l * WIDTH * WIDTH, part);
    k_gemv_fin<<<16, 256, 0, stream>>>(part, ln1_w + (size_t)l * WIDTH, scl, 1);
    k_rmsnorm<<<ROWS, 256, 0, stream>>>(h, scl, nb);

    // qkv
    hipMemsetAsync(qb, 0, (size_t)(409600 + 51200 + 51200) * 4, stream);
    k_gemm<<<dim3(4, 13, 4), 256, 0, stream>>>(nb, wq_l, qb, WIDTH, NH * HD);
    k_gemm<<<dim3(1, 13, 4), 256, 0, stream>>>(nb, wk_l, ksuf, WIDTH, HD);
    k_gemm<<<dim3(1, 13, 4), 256, 0, stream>>>(nb, wv_l, vsuf, WIDTH, HD);
    k_rope<<<800, 256, 0, stream>>>(qb, NH);
    k_rope<<<100, 256, 0, stream>>>(ksuf, 1);

    k_attn<<<ROWS, 256, 0, stream>>>(qb, ksuf, vsuf, past_keys, past_values, ob, l);
    k_gemm<<<dim3(2, 13, 8), 256, 0, stream>>>(ob, wo_l, h, NH * HD, WIDTH);  // residual add

    // adaRMS 2 + MLP
    k_gemv_part<<<dim3(4, 16, BZ), 256, 0, stream>>>(cond, ln2_ada + (size_t)l * WIDTH * WIDTH, part);
    k_gemv_fin<<<16, 256, 0, stream>>>(part, ln2_w + (size_t)l * WIDTH, scl, 1);
    k_rmsnorm<<<ROWS, 256, 0, stream>>>(h, scl, nb);

    hipMemsetAsync(mlp_g, 0, (size_t)(819200 + 819200) * 4, stream);
    k_gemm<<<dim3(8, 13, 4), 256, 0, stream>>>(nb, wg_l, mlp_g, WIDTH, MLP_DIM);
    k_gemm<<<dim3(8, 13, 4), 256, 0, stream>>>(nb, wu_l, mlp_u, WIDTH, MLP_DIM);
    k_gelumul<<<3200, 256, 0, stream>>>(mlp_g, mlp_u);
    k_gemm<<<dim3(2, 13, 16), 256, 0, stream>>>(mlp_g, wd_l, h, MLP_DIM, WIDTH); // residual add
  }

  // final norm + projection
  k_gemv_part<<<dim3(4, 16, BZ), 256, 0, stream>>>(cond, fin_ada, part);
  k_gemv_fin<<<16, 256, 0, stream>>>(part, fin_w, scl, 1);
  k_rmsnorm<<<ROWS, 256, 0, stream>>>(h, scl, nb);
  k_out<<<ROWS, 256, 0, stream>>>(nb, w_act_out, b_act_out, out);
}